// Round 1
// baseline (457.185 us; speedup 1.0000x reference)
//
#include <hip/hip_runtime.h>
#include <hip/hip_bf16.h>
#include <stdint.h>

#define HWsz 3136
#define Hh   56
#define Cc   384
#define C3   1152
#define NHEADS 6
#define NB   8

typedef __attribute__((ext_vector_type(8))) short short8;
typedef __attribute__((ext_vector_type(4))) short short4v;
typedef __attribute__((ext_vector_type(4))) float f32x4;

static __device__ __forceinline__ float bf2f(short s) {
  unsigned u = ((unsigned)(unsigned short)s) << 16;
  return __builtin_bit_cast(float, u);
}
static __device__ __forceinline__ short f2bf(float f) {
  __hip_bfloat16 h = __float2bfloat16(f);
  return (short)__builtin_bit_cast(unsigned short, h);
}

// ---------------- weight conversion (fold q-scale 0.125 into first 384 rows of w_qkv)
__global__ void prep_weights(const float* __restrict__ wq, const float* __restrict__ wp,
                             short* __restrict__ wqb, short* __restrict__ wpb) {
  int stride = gridDim.x * blockDim.x;
  for (int i = blockIdx.x * blockDim.x + threadIdx.x; i < C3 * Cc; i += stride) {
    float v = wq[i];
    if (i < Cc * Cc) v *= 0.125f;   // rows o<384 are q
    wqb[i] = f2bf(v);
  }
  for (int i = blockIdx.x * blockDim.x + threadIdx.x; i < Cc * Cc; i += stride)
    wpb[i] = f2bf(wp[i]);
}

// ---------------- x (B,C,HW) f32 -> xT (B,HW,C) bf16
__global__ __launch_bounds__(256) void transpose_x(const float* __restrict__ x, short* __restrict__ xT) {
  __shared__ float tile[32][33];
  int b = blockIdx.z;
  int p0 = blockIdx.x * 32, c0 = blockIdx.y * 32;
  int t = threadIdx.x;
  const float* xb = x + (size_t)b * Cc * HWsz;
  int tp = t & 31, tc = t >> 5;
#pragma unroll
  for (int cc = 0; cc < 4; ++cc)
    tile[tc + cc * 8][tp] = xb[(size_t)(c0 + tc + cc * 8) * HWsz + p0 + tp];
  __syncthreads();
  short* xo = xT + (size_t)b * HWsz * Cc;
  int wc = t & 31, wp = t >> 5;
#pragma unroll
  for (int pp = 0; pp < 4; ++pp)
    xo[(size_t)(p0 + wp + pp * 8) * Cc + c0 + wc] = f2bf(tile[wc][wp + pp * 8]);
}

// ---------------- bf16 MFMA GEMM: D[o,p] = sum_k A[o][k]*Brow[p][k]
// MODE 0: out = qkv bf16 [b][p][1152], bias scaled for o<384
// MODE 1: out = f32 [b][o][3136], bias plain
template<int MODE>
__global__ __launch_bounds__(256) void gemm_bf16(
    const short* __restrict__ A,      // [M][384] bf16 rows
    const short* __restrict__ Bm,     // [NB][3136][384] bf16 rows
    const float* __restrict__ bias,   // [M] f32
    void* __restrict__ outp)
{
  constexpr int K = Cc;
  const int b   = blockIdx.z;
  const int om0 = blockIdx.x * 128;
  const int pn0 = blockIdx.y * 128;
  __shared__ short lA[128 * 40];   // 80B rows: stride-80 -> conflict-light
  __shared__ short lB[128 * 40];
  const int t    = threadIdx.x;
  const int lane = t & 63;
  const int wave = t >> 6;
  const int wm = (wave >> 1) * 64;
  const int wn = (wave & 1) * 64;
  f32x4 acc[4][4] = {};
  const short* Bb = Bm + (size_t)b * HWsz * K;
  const int sr = t >> 2;          // staging row 0..63 (and +64)
  const int sk = (t & 3) * 8;     // k element offset {0,8,16,24}
  int pr0 = pn0 + sr;      if (pr0 > HWsz - 1) pr0 = HWsz - 1;
  int pr1 = pn0 + sr + 64; if (pr1 > HWsz - 1) pr1 = HWsz - 1;
  const int fr = lane & 15;
  const int fo = lane >> 4;
  for (int k0 = 0; k0 < K; k0 += 32) {
    short8 a0 = *(const short8*)(A + (size_t)(om0 + sr) * K + k0 + sk);
    short8 a1 = *(const short8*)(A + (size_t)(om0 + sr + 64) * K + k0 + sk);
    short8 b0 = *(const short8*)(Bb + (size_t)pr0 * K + k0 + sk);
    short8 b1 = *(const short8*)(Bb + (size_t)pr1 * K + k0 + sk);
    __syncthreads();                 // previous iter's frag reads done
    *(short8*)(lA + sr * 40 + sk) = a0;
    *(short8*)(lA + (sr + 64) * 40 + sk) = a1;
    *(short8*)(lB + sr * 40 + sk) = b0;
    *(short8*)(lB + (sr + 64) * 40 + sk) = b1;
    __syncthreads();
    short8 af[4], bfr[4];
#pragma unroll
    for (int m = 0; m < 4; ++m) af[m]  = *(const short8*)(lA + (wm + m * 16 + fr) * 40 + fo * 8);
#pragma unroll
    for (int n = 0; n < 4; ++n) bfr[n] = *(const short8*)(lB + (wn + n * 16 + fr) * 40 + fo * 8);
#pragma unroll
    for (int m = 0; m < 4; ++m)
#pragma unroll
      for (int n = 0; n < 4; ++n)
        acc[m][n] = __builtin_amdgcn_mfma_f32_16x16x32_bf16(af[m], bfr[n], acc[m][n], 0, 0, 0);
  }
  // epilogue: lane holds D[rows ob..ob+3][col p];  C/D map: col=lane&15, row=(lane>>4)*4+r
  if (MODE == 0) {
    short* outq = (short*)outp + (size_t)b * HWsz * C3;
#pragma unroll
    for (int m = 0; m < 4; ++m) {
      int ob = om0 + wm + m * 16 + (lane >> 4) * 4;
      float bs[4];
#pragma unroll
      for (int r = 0; r < 4; ++r) {
        int o = ob + r;
        bs[r] = bias[o] * (o < Cc ? 0.125f : 1.0f);
      }
#pragma unroll
      for (int n = 0; n < 4; ++n) {
        int p = pn0 + wn + n * 16 + fr;
        if (p < HWsz) {
          short4v s;
#pragma unroll
          for (int r = 0; r < 4; ++r) s[r] = f2bf(acc[m][n][r] + bs[r]);
          *(short4v*)(outq + (size_t)p * C3 + ob) = s;   // 4 consecutive o -> 8B store
        }
      }
    }
  } else {
    float* outo = (float*)outp + (size_t)b * Cc * HWsz;
#pragma unroll
    for (int m = 0; m < 4; ++m) {
      int ob = om0 + wm + m * 16 + (lane >> 4) * 4;
#pragma unroll
      for (int n = 0; n < 4; ++n) {
        int p = pn0 + wn + n * 16 + fr;
        if (p < HWsz) {
#pragma unroll
          for (int r = 0; r < 4; ++r)
            outo[(size_t)(ob + r) * HWsz + p] = acc[m][n][r] + bias[ob + r];
        }
      }
    }
  }
}

// ---------------- fused neighborhood attention: scores -> softmax -> PV
// qkv[b][p][1152] bf16 (q pre-scaled); out aout[b][p][384] bf16
__global__ __launch_bounds__(256) void attn_kernel(const short* __restrict__ qkv,
                                                   short* __restrict__ aout) {
  __shared__ float lsc[49 * 256];
  const int bh = blockIdx.z;
  const int b = bh / NHEADS, h = bh % NHEADS;
  const int i = blockIdx.y * 16 + (threadIdx.x >> 4);
  const int j = blockIdx.x * 16 + (threadIdx.x & 15);
  if (i >= Hh || j >= Hh) return;          // no barriers below: safe early-exit
  const int t = threadIdx.x;
  const size_t rowb = (size_t)b * HWsz;
  const short* qrow = qkv + (rowb + i * Hh + j) * C3 + h * 64;
  float q[64];
#pragma unroll
  for (int d8 = 0; d8 < 8; ++d8) {
    short8 v = ((const short8*)qrow)[d8];
#pragma unroll
    for (int e = 0; e < 8; ++e) q[d8 * 8 + e] = bf2f(v[e]);
  }
  // scores (OOB neighbors score 0, matching zero-padded k)
#pragma unroll 1
  for (int dy = 0; dy < 7; ++dy) {
    int ii = i + dy - 3;
#pragma unroll 1
    for (int dx = 0; dx < 7; ++dx) {
      int jj = j + dx - 3;
      float s = 0.f;
      if (ii >= 0 && ii < Hh && jj >= 0 && jj < Hh) {
        const short8* kp = (const short8*)(qkv + (rowb + ii * Hh + jj) * C3 + Cc + h * 64);
#pragma unroll
        for (int d8 = 0; d8 < 8; ++d8) {
          short8 kv = kp[d8];
#pragma unroll
          for (int e = 0; e < 8; ++e) s += q[d8 * 8 + e] * bf2f(kv[e]);
        }
      }
      lsc[(dy * 7 + dx) * 256 + t] = s;
    }
  }
  float mx = -1e30f;
#pragma unroll 1
  for (int idx = 0; idx < 49; ++idx) mx = fmaxf(mx, lsc[idx * 256 + t]);
  float sum = 0.f;
#pragma unroll 1
  for (int idx = 0; idx < 49; ++idx) sum += __expf(lsc[idx * 256 + t] - mx);
  float rinv = 1.0f / sum;
  float o[64];
#pragma unroll
  for (int d = 0; d < 64; ++d) o[d] = 0.f;
#pragma unroll 1
  for (int dy = 0; dy < 7; ++dy) {
    int ii = i + dy - 3;
    if (ii < 0 || ii >= Hh) continue;
#pragma unroll 1
    for (int dx = 0; dx < 7; ++dx) {
      int jj = j + dx - 3;
      if (jj < 0 || jj >= Hh) continue;
      float w = __expf(lsc[(dy * 7 + dx) * 256 + t] - mx) * rinv;
      const short8* vp = (const short8*)(qkv + (rowb + ii * Hh + jj) * C3 + 2 * Cc + h * 64);
#pragma unroll
      for (int d8 = 0; d8 < 8; ++d8) {
        short8 vv = vp[d8];
#pragma unroll
        for (int e = 0; e < 8; ++e) o[d8 * 8 + e] += w * bf2f(vv[e]);
      }
    }
  }
  short* orow = aout + (rowb + i * Hh + j) * Cc + h * 64;
#pragma unroll
  for (int d8 = 0; d8 < 8; ++d8) {
    short8 s;
#pragma unroll
    for (int e = 0; e < 8; ++e) s[e] = f2bf(o[d8 * 8 + e]);
    ((short8*)orow)[d8] = s;
  }
}

extern "C" void kernel_launch(void* const* d_in, const int* in_sizes, int n_in,
                              void* d_out, int out_size, void* d_ws, size_t ws_size,
                              hipStream_t stream) {
  const float* x      = (const float*)d_in[0];
  const float* w_qkv  = (const float*)d_in[1];
  const float* b_qkv  = (const float*)d_in[2];
  const float* w_proj = (const float*)d_in[3];
  const float* b_proj = (const float*)d_in[4];
  // d_in[5] = bias_table, multiplied by 0.0 in reference -> ignored

  char* ws = (char*)d_ws;
  // layout: qkv 57,802,752 | xT/attn_out 19,267,584 | wq_b 884,736 | wp_b 294,912  (~78.25 MB)
  short* qkv = (short*)ws;
  short* xT  = (short*)(ws + 57802752);
  short* wqb = (short*)(ws + 57802752 + 19267584);
  short* wpb = (short*)(ws + 57802752 + 19267584 + 884736);

  prep_weights<<<512, 256, 0, stream>>>(w_qkv, w_proj, wqb, wpb);
  transpose_x<<<dim3(98, 12, NB), 256, 0, stream>>>(x, xT);
  gemm_bf16<0><<<dim3(9, 25, NB), 256, 0, stream>>>(wqb, xT, b_qkv, qkv);
  attn_kernel<<<dim3(4, 4, NB * NHEADS), 256, 0, stream>>>(qkv, xT);  // xT reused as attn_out
  gemm_bf16<1><<<dim3(3, 25, NB), 256, 0, stream>>>(wpb, xT, b_proj, d_out);
}

// Round 2
// 321.935 us; speedup vs baseline: 1.4201x; 1.4201x over previous
//
#include <hip/hip_runtime.h>
#include <hip/hip_bf16.h>
#include <stdint.h>

#define HWsz 3136
#define Hh   56
#define Cc   384
#define C3   1152
#define NHEADS 6
#define NB   8

typedef __attribute__((ext_vector_type(8))) short short8;
typedef __attribute__((ext_vector_type(4))) short short4v;
typedef __attribute__((ext_vector_type(4))) float f32x4;
typedef __attribute__((ext_vector_type(4))) int int4v;

static __device__ __forceinline__ float bf2f(short s) {
  unsigned u = ((unsigned)(unsigned short)s) << 16;
  return __builtin_bit_cast(float, u);
}
static __device__ __forceinline__ short f2bf(float f) {
  __hip_bfloat16 h = __float2bfloat16(f);
  return (short)__builtin_bit_cast(unsigned short, h);
}
// 8 bf16 (as int4) -> 8 f32, 1 VALU op per element (shift / mask)
static __device__ __forceinline__ void cvt8(int4v v, float* f) {
#pragma unroll
  for (int e = 0; e < 4; ++e) {
    unsigned u = (unsigned)v[e];
    f[2 * e]     = __builtin_bit_cast(float, u << 16);
    f[2 * e + 1] = __builtin_bit_cast(float, u & 0xffff0000u);
  }
}

// ---------------- weight conversion (fold q-scale 0.125 into first 384 rows of w_qkv)
__global__ void prep_weights(const float* __restrict__ wq, const float* __restrict__ wp,
                             short* __restrict__ wqb, short* __restrict__ wpb) {
  int stride = gridDim.x * blockDim.x;
  for (int i = blockIdx.x * blockDim.x + threadIdx.x; i < C3 * Cc; i += stride) {
    float v = wq[i];
    if (i < Cc * Cc) v *= 0.125f;   // rows o<384 are q
    wqb[i] = f2bf(v);
  }
  for (int i = blockIdx.x * blockDim.x + threadIdx.x; i < Cc * Cc; i += stride)
    wpb[i] = f2bf(wp[i]);
}

// ---------------- x (B,C,HW) f32 -> xT (B,HW,C) bf16
__global__ __launch_bounds__(256) void transpose_x(const float* __restrict__ x, short* __restrict__ xT) {
  __shared__ float tile[32][33];
  int b = blockIdx.z;
  int p0 = blockIdx.x * 32, c0 = blockIdx.y * 32;
  int t = threadIdx.x;
  const float* xb = x + (size_t)b * Cc * HWsz;
  int tp = t & 31, tc = t >> 5;
#pragma unroll
  for (int cc = 0; cc < 4; ++cc)
    tile[tc + cc * 8][tp] = xb[(size_t)(c0 + tc + cc * 8) * HWsz + p0 + tp];
  __syncthreads();
  short* xo = xT + (size_t)b * HWsz * Cc;
  int wc = t & 31, wp = t >> 5;
#pragma unroll
  for (int pp = 0; pp < 4; ++pp)
    xo[(size_t)(p0 + wp + pp * 8) * Cc + c0 + wc] = f2bf(tile[wc][wp + pp * 8]);
}

// ---------------- bf16 MFMA GEMM: D[o,p] = sum_k A[o][k]*Brow[p][k]
// MODE 0: out = qkv bf16 [b][p][1152], bias scaled for o<384
// MODE 1: out = f32 [b][o][3136], bias plain
template<int MODE>
__global__ __launch_bounds__(256) void gemm_bf16(
    const short* __restrict__ A,      // [M][384] bf16 rows
    const short* __restrict__ Bm,     // [NB][3136][384] bf16 rows
    const float* __restrict__ bias,   // [M] f32
    void* __restrict__ outp)
{
  constexpr int K = Cc;
  const int b   = blockIdx.z;
  const int om0 = blockIdx.x * 128;
  const int pn0 = blockIdx.y * 128;
  __shared__ short lA[128 * 40];   // 80B rows: stride-80 -> conflict-light
  __shared__ short lB[128 * 40];
  const int t    = threadIdx.x;
  const int lane = t & 63;
  const int wave = t >> 6;
  const int wm = (wave >> 1) * 64;
  const int wn = (wave & 1) * 64;
  f32x4 acc[4][4] = {};
  const short* Bb = Bm + (size_t)b * HWsz * K;
  const int sr = t >> 2;          // staging row 0..63 (and +64)
  const int sk = (t & 3) * 8;     // k element offset {0,8,16,24}
  int pr0 = pn0 + sr;      if (pr0 > HWsz - 1) pr0 = HWsz - 1;
  int pr1 = pn0 + sr + 64; if (pr1 > HWsz - 1) pr1 = HWsz - 1;
  const int fr = lane & 15;
  const int fo = lane >> 4;
  for (int k0 = 0; k0 < K; k0 += 32) {
    short8 a0 = *(const short8*)(A + (size_t)(om0 + sr) * K + k0 + sk);
    short8 a1 = *(const short8*)(A + (size_t)(om0 + sr + 64) * K + k0 + sk);
    short8 b0 = *(const short8*)(Bb + (size_t)pr0 * K + k0 + sk);
    short8 b1 = *(const short8*)(Bb + (size_t)pr1 * K + k0 + sk);
    __syncthreads();                 // previous iter's frag reads done
    *(short8*)(lA + sr * 40 + sk) = a0;
    *(short8*)(lA + (sr + 64) * 40 + sk) = a1;
    *(short8*)(lB + sr * 40 + sk) = b0;
    *(short8*)(lB + (sr + 64) * 40 + sk) = b1;
    __syncthreads();
    short8 af[4], bfr[4];
#pragma unroll
    for (int m = 0; m < 4; ++m) af[m]  = *(const short8*)(lA + (wm + m * 16 + fr) * 40 + fo * 8);
#pragma unroll
    for (int n = 0; n < 4; ++n) bfr[n] = *(const short8*)(lB + (wn + n * 16 + fr) * 40 + fo * 8);
#pragma unroll
    for (int m = 0; m < 4; ++m)
#pragma unroll
      for (int n = 0; n < 4; ++n)
        acc[m][n] = __builtin_amdgcn_mfma_f32_16x16x32_bf16(af[m], bfr[n], acc[m][n], 0, 0, 0);
  }
  // epilogue: lane holds D[rows ob..ob+3][col p];  C/D map: col=lane&15, row=(lane>>4)*4+r
  if (MODE == 0) {
    short* outq = (short*)outp + (size_t)b * HWsz * C3;
#pragma unroll
    for (int m = 0; m < 4; ++m) {
      int ob = om0 + wm + m * 16 + (lane >> 4) * 4;
      float bs[4];
#pragma unroll
      for (int r = 0; r < 4; ++r) {
        int o = ob + r;
        bs[r] = bias[o] * (o < Cc ? 0.125f : 1.0f);
      }
#pragma unroll
      for (int n = 0; n < 4; ++n) {
        int p = pn0 + wn + n * 16 + fr;
        if (p < HWsz) {
          short4v s;
#pragma unroll
          for (int r = 0; r < 4; ++r) s[r] = f2bf(acc[m][n][r] + bs[r]);
          *(short4v*)(outq + (size_t)p * C3 + ob) = s;   // 4 consecutive o -> 8B store
        }
      }
    }
  } else {
    float* outo = (float*)outp + (size_t)b * Cc * HWsz;
#pragma unroll
    for (int m = 0; m < 4; ++m) {
      int ob = om0 + wm + m * 16 + (lane >> 4) * 4;
#pragma unroll
      for (int n = 0; n < 4; ++n) {
        int p = pn0 + wn + n * 16 + fr;
        if (p < HWsz) {
#pragma unroll
          for (int r = 0; r < 4; ++r)
            outo[(size_t)(ob + r) * HWsz + p] = acc[m][n][r] + bias[ob + r];
        }
      }
    }
  }
}

// ---------------- fused neighborhood attention, single pass, register-resident
// qkv[b][p][1152] bf16 (q pre-scaled); out aout[b][p][384] bf16
// 2 threads per position: half=t&1 owns dims [half*32, half*32+32).
// No-max softmax: scores are O(0.5) (q scaled by 1/8), exp(s) is safe and
// softmax is shift-invariant -> identical result. OOB taps: score 0 -> sum+=1.
__global__ __launch_bounds__(256) void attn_kernel(const short* __restrict__ qkv,
                                                   short* __restrict__ aout) {
  const int bh = blockIdx.z;
  const int b = bh / NHEADS, h = bh % NHEADS;
  const int t = threadIdx.x;
  const int pos = t >> 1;          // 0..127 within 16x8 tile
  const int half = t & 1;          // dim half
  const int i = blockIdx.y * 8 + (pos >> 4);
  const int j = blockIdx.x * 16 + (pos & 15);
  if (j >= Hh) return;             // no barriers: safe early-exit (i always < 56)
  const size_t rowb = (size_t)b * HWsz;
  const int dof = h * 64 + half * 32;            // channel offset of my 32 dims

  float q[32];
  {
    const int4v* qp = (const int4v*)(qkv + (rowb + i * Hh + j) * C3 + dof);
#pragma unroll
    for (int w = 0; w < 4; ++w) { int4v v = qp[w]; cvt8(v, q + w * 8); }
  }
  float o[32];
#pragma unroll
  for (int d = 0; d < 32; ++d) o[d] = 0.f;
  float sum = 0.f;

#pragma unroll 1
  for (int dy = 0; dy < 7; ++dy) {
    const int ii = i + dy - 3;
    const bool iok = (unsigned)ii < (unsigned)Hh;
    // K base for this row at dx=0 (jj=j-3); V is +Cc elements
    const short* krow0 = qkv + (rowb + (size_t)ii * Hh + (j - 3)) * C3 + Cc + dof;
#pragma unroll
    for (int dx = 0; dx < 7; ++dx) {
      const int jj = j + dx - 3;
      if (iok && (unsigned)jj < (unsigned)Hh) {
        const int4v* kp = (const int4v*)(krow0 + dx * C3);
        int4v k0 = kp[0], k1 = kp[1], k2 = kp[2], k3 = kp[3];
        float kf[32];
        cvt8(k0, kf); cvt8(k1, kf + 8); cvt8(k2, kf + 16); cvt8(k3, kf + 24);
        // 4-way partial dot for ILP
        float s0 = 0.f, s1 = 0.f, s2 = 0.f, s3 = 0.f;
#pragma unroll
        for (int d = 0; d < 8; ++d) {
          s0 += q[d]      * kf[d];
          s1 += q[d + 8]  * kf[d + 8];
          s2 += q[d + 16] * kf[d + 16];
          s3 += q[d + 24] * kf[d + 24];
        }
        float s = (s0 + s1) + (s2 + s3);
        s += __shfl_xor(s, 1);           // combine the two dim-halves
        float e = __expf(s);
        sum += e;
        const int4v* vp = (const int4v*)(krow0 + dx * C3 + Cc);
        int4v v0 = vp[0], v1 = vp[1], v2 = vp[2], v3 = vp[3];
        float vf[32];
        cvt8(v0, vf); cvt8(v1, vf + 8); cvt8(v2, vf + 16); cvt8(v3, vf + 24);
#pragma unroll
        for (int d = 0; d < 32; ++d) o[d] += e * vf[d];
      } else {
        sum += 1.0f;                     // exp(0) for zero-padded K
      }
    }
  }
  float r = 1.0f / sum;
  short* orow = aout + (rowb + i * Hh + j) * Cc + dof;
#pragma unroll
  for (int w = 0; w < 4; ++w) {
    short8 s;
#pragma unroll
    for (int e = 0; e < 8; ++e) s[e] = f2bf(o[w * 8 + e] * r);
    ((short8*)orow)[w] = s;
  }
}

extern "C" void kernel_launch(void* const* d_in, const int* in_sizes, int n_in,
                              void* d_out, int out_size, void* d_ws, size_t ws_size,
                              hipStream_t stream) {
  const float* x      = (const float*)d_in[0];
  const float* w_qkv  = (const float*)d_in[1];
  const float* b_qkv  = (const float*)d_in[2];
  const float* w_proj = (const float*)d_in[3];
  const float* b_proj = (const float*)d_in[4];
  // d_in[5] = bias_table, multiplied by 0.0 in reference -> ignored

  char* ws = (char*)d_ws;
  // layout: qkv 57,802,752 | xT/attn_out 19,267,584 | wq_b 884,736 | wp_b 294,912  (~78.25 MB)
  short* qkv = (short*)ws;
  short* xT  = (short*)(ws + 57802752);
  short* wqb = (short*)(ws + 57802752 + 19267584);
  short* wpb = (short*)(ws + 57802752 + 19267584 + 884736);

  prep_weights<<<512, 256, 0, stream>>>(w_qkv, w_proj, wqb, wpb);
  transpose_x<<<dim3(98, 12, NB), 256, 0, stream>>>(x, xT);
  gemm_bf16<0><<<dim3(9, 25, NB), 256, 0, stream>>>(wqb, xT, b_qkv, qkv);
  attn_kernel<<<dim3(4, 7, NB * NHEADS), 256, 0, stream>>>(qkv, xT);  // xT reused as attn_out
  gemm_bf16<1><<<dim3(3, 25, NB), 256, 0, stream>>>(wpb, xT, b_proj, d_out);
}

// Round 3
// 256.370 us; speedup vs baseline: 1.7833x; 1.2557x over previous
//
#include <hip/hip_runtime.h>
#include <hip/hip_bf16.h>
#include <stdint.h>

#define HWsz 3136
#define Hh   56
#define Cc   384
#define NHEADS 6
#define NB   8

typedef __attribute__((ext_vector_type(8))) short short8;
typedef __attribute__((ext_vector_type(4))) short short4v;
typedef __attribute__((ext_vector_type(4))) float f32x4;

static __device__ __forceinline__ short f2bf(float f) {
  __hip_bfloat16 h = __float2bfloat16(f);
  return (short)__builtin_bit_cast(unsigned short, h);
}

// ---------------- weight conversion (fold q-scale 0.125 into first 384 rows of w_qkv)
__global__ void prep_weights(const float* __restrict__ wq, const float* __restrict__ wp,
                             short* __restrict__ wqb, short* __restrict__ wpb) {
  int stride = gridDim.x * blockDim.x;
  for (int i = blockIdx.x * blockDim.x + threadIdx.x; i < 3 * Cc * Cc; i += stride) {
    float v = wq[i];
    if (i < Cc * Cc) v *= 0.125f;
    wqb[i] = f2bf(v);
  }
  for (int i = blockIdx.x * blockDim.x + threadIdx.x; i < Cc * Cc; i += stride)
    wpb[i] = f2bf(wp[i]);
}

// ---------------- x (B,C,HW) f32 -> xT (B,HW,C) bf16
__global__ __launch_bounds__(256) void transpose_x(const float* __restrict__ x, short* __restrict__ xT) {
  __shared__ float tile[32][33];
  int b = blockIdx.z;
  int p0 = blockIdx.x * 32, c0 = blockIdx.y * 32;
  int t = threadIdx.x;
  const float* xb = x + (size_t)b * Cc * HWsz;
  int tp = t & 31, tc = t >> 5;
#pragma unroll
  for (int cc = 0; cc < 4; ++cc)
    tile[tc + cc * 8][tp] = xb[(size_t)(c0 + tc + cc * 8) * HWsz + p0 + tp];
  __syncthreads();
  short* xo = xT + (size_t)b * HWsz * Cc;
  int wc = t & 31, wp = t >> 5;
#pragma unroll
  for (int pp = 0; pp < 4; ++pp)
    xo[(size_t)(p0 + wp + pp * 8) * Cc + c0 + wc] = f2bf(tile[wc][wp + pp * 8]);
}

// ---------------- bf16 MFMA GEMM: D[o,p] = sum_k A[o][k]*Brow[p][k], K=384
// MODE 0: o<768 -> qk[b][p][768] bf16 (bias, q-rows scaled); o>=768 -> vtp[b][ch][62][64] (padded image)
// MODE 1: out f32 [b][o][3136], bias plain
template<int MODE>
__global__ __launch_bounds__(256) void gemm_bf16(
    const short* __restrict__ A, const short* __restrict__ Bm,
    const float* __restrict__ bias, void* __restrict__ o1, void* __restrict__ o2)
{
  constexpr int K = Cc;
  const int b   = blockIdx.z;
  const int om0 = blockIdx.x * 128;
  const int pn0 = blockIdx.y * 128;
  __shared__ short lA[128 * 40];
  __shared__ short lB[128 * 40];
  const int t    = threadIdx.x;
  const int lane = t & 63;
  const int wave = t >> 6;
  const int wm = (wave >> 1) * 64;
  const int wn = (wave & 1) * 64;
  f32x4 acc[4][4] = {};
  const short* Bb = Bm + (size_t)b * HWsz * K;
  const int sr = t >> 2;
  const int sk = (t & 3) * 8;
  int pr0 = pn0 + sr;      if (pr0 > HWsz - 1) pr0 = HWsz - 1;
  int pr1 = pn0 + sr + 64; if (pr1 > HWsz - 1) pr1 = HWsz - 1;
  const int fr = lane & 15;
  const int fo = lane >> 4;
  for (int k0 = 0; k0 < K; k0 += 32) {
    short8 a0 = *(const short8*)(A + (size_t)(om0 + sr) * K + k0 + sk);
    short8 a1 = *(const short8*)(A + (size_t)(om0 + sr + 64) * K + k0 + sk);
    short8 b0 = *(const short8*)(Bb + (size_t)pr0 * K + k0 + sk);
    short8 b1 = *(const short8*)(Bb + (size_t)pr1 * K + k0 + sk);
    __syncthreads();
    *(short8*)(lA + sr * 40 + sk) = a0;
    *(short8*)(lA + (sr + 64) * 40 + sk) = a1;
    *(short8*)(lB + sr * 40 + sk) = b0;
    *(short8*)(lB + (sr + 64) * 40 + sk) = b1;
    __syncthreads();
    short8 af[4], bfr[4];
#pragma unroll
    for (int m = 0; m < 4; ++m) af[m]  = *(const short8*)(lA + (wm + m * 16 + fr) * 40 + fo * 8);
#pragma unroll
    for (int n = 0; n < 4; ++n) bfr[n] = *(const short8*)(lB + (wn + n * 16 + fr) * 40 + fo * 8);
#pragma unroll
    for (int m = 0; m < 4; ++m)
#pragma unroll
      for (int n = 0; n < 4; ++n)
        acc[m][n] = __builtin_amdgcn_mfma_f32_16x16x32_bf16(af[m], bfr[n], acc[m][n], 0, 0, 0);
  }
  if (MODE == 0) {
    if (om0 < 768) {     // q & k -> qk[b][p][768]
      short* outq = (short*)o1 + (size_t)b * HWsz * 768;
#pragma unroll
      for (int m = 0; m < 4; ++m) {
        int ob = om0 + wm + m * 16 + (lane >> 4) * 4;
        float bs[4];
#pragma unroll
        for (int r = 0; r < 4; ++r) { int o = ob + r; bs[r] = bias[o] * (o < Cc ? 0.125f : 1.0f); }
#pragma unroll
        for (int n = 0; n < 4; ++n) {
          int p = pn0 + wn + n * 16 + fr;
          if (p < HWsz) {
            short4v s;
#pragma unroll
            for (int r = 0; r < 4; ++r) s[r] = f2bf(acc[m][n][r] + bs[r]);
            *(short4v*)(outq + (size_t)p * 768 + ob) = s;
          }
        }
      }
    } else {             // v -> vtp[b][ch][62][64] padded (border pre-zeroed)
      short* vtp = (short*)o2;
#pragma unroll
      for (int m = 0; m < 4; ++m) {
        int ob = om0 + wm + m * 16 + (lane >> 4) * 4;
#pragma unroll
        for (int n = 0; n < 4; ++n) {
          int p = pn0 + wn + n * 16 + fr;
          if (p < HWsz) {
            int ii = p / Hh, jj = p % Hh;
#pragma unroll
            for (int r = 0; r < 4; ++r) {
              int ch = ob + r - 768;
              vtp[((b * Cc + ch) * 62 + ii + 3) * 64 + jj + 3] = f2bf(acc[m][n][r] + bias[ob + r]);
            }
          }
        }
      }
    }
  } else {
    float* outo = (float*)o1 + (size_t)b * Cc * HWsz;
#pragma unroll
    for (int m = 0; m < 4; ++m) {
      int ob = om0 + wm + m * 16 + (lane >> 4) * 4;
#pragma unroll
      for (int n = 0; n < 4; ++n) {
        int p = pn0 + wn + n * 16 + fr;
        if (p < HWsz) {
#pragma unroll
          for (int r = 0; r < 4; ++r)
            outo[(size_t)(ob + r) * HWsz + p] = acc[m][n][r] + bias[ob + r];
        }
      }
    }
  }
}

// ---------------- MFMA neighborhood attention
// Block = (b,h, 8x8 query tile). 4 waves x 16 queries. Keys: 14x16 padded patch = 224 = 7 chunks of 32.
// S^T = K x Q (D: col=query=lane&15, row=key_local). No-max softmax; window mask per-lane.
// P chunk -> wave-private LDS rows -> A-frags for PV = P x V (V frags from padded Vtp). No barriers.
__global__ __launch_bounds__(256) void attn_mfma(
    const short* __restrict__ qkv,  // [b][3136][768] (q|k)
    const short* __restrict__ vtp,  // [b][384][62][64]
    short* __restrict__ aout)       // [b][3136][384]
{
  __shared__ short P[64 * 40];      // [query][40] (32 keys + pad)
  const int bh = blockIdx.z;
  const int b = bh / NHEADS, h = bh % NHEADS;
  const int i0 = blockIdx.y * 8, j0 = blockIdx.x * 8;
  const int t = threadIdx.x, lane = t & 63, w = t >> 6;
  const int fr = lane & 15, fo = lane >> 4;

  const int q_idx = w * 16 + fr;              // this lane's B-col query (and P row)
  const int qr = q_idx >> 3, qc = q_idx & 7;
  const int qkvb = b * HWsz * 768;

  // Q B-frags (regs, reused all chunks)
  const short* qp = qkv + qkvb + ((i0 + qr) * Hh + j0 + qc) * 768 + h * 64 + fo * 8;
  short8 qf0 = *(const short8*)(qp);
  short8 qf1 = *(const short8*)(qp + 32);

  // K frag column: pc = fr
  const int kj = j0 + fr - 3;
  const bool jok = (unsigned)kj < (unsigned)Hh;
  const int kjs = kj < 0 ? 0 : (kj > Hh - 1 ? Hh - 1 : kj);
  const short* kcol = qkv + qkvb + Cc + h * 64 + fo * 8;

  const short8 z = (short8)0;
  f32x4 oacc[4] = {};
  float sum = 0.f;

#pragma unroll 2
  for (int kc = 0; kc < 7; ++kc) {
    // --- K A-frags (global, clamped+zeroed for image-OOB)
    short8 kf[2][2];
#pragma unroll
    for (int mloc = 0; mloc < 2; ++mloc) {
      int ki = i0 + 2 * kc + mloc - 3;
      bool ok = jok && ((unsigned)ki < (unsigned)Hh);
      int kis = ki < 0 ? 0 : (ki > Hh - 1 ? Hh - 1 : ki);
      const short8* ka = (const short8*)(kcol + (kis * Hh + kjs) * 768);
      short8 k0 = ka[0], k1 = ka[4];
      kf[mloc][0] = ok ? k0 : z;
      kf[mloc][1] = ok ? k1 : z;
    }
    // --- V B-frags (global from padded Vtp; always in-bounds)
    short8 vf[4];
    const int vrow = i0 + 2 * kc + (fo >> 1);
    const int vcol = j0 + (fo & 1) * 8;
#pragma unroll
    for (int n = 0; n < 4; ++n)
      vf[n] = *(const short8*)(vtp + ((b * Cc + h * 64 + 16 * n + fr) * 62 + vrow) * 64 + vcol);
    // --- QK^T
    f32x4 s0 = {}, s1 = {};
    s0 = __builtin_amdgcn_mfma_f32_16x16x32_bf16(kf[0][0], qf0, s0, 0, 0, 0);
    s0 = __builtin_amdgcn_mfma_f32_16x16x32_bf16(kf[0][1], qf1, s0, 0, 0, 0);
    s1 = __builtin_amdgcn_mfma_f32_16x16x32_bf16(kf[1][0], qf0, s1, 0, 0, 0);
    s1 = __builtin_amdgcn_mfma_f32_16x16x32_bf16(kf[1][1], qf1, s1, 0, 0, 0);
    // --- window mask + exp + pack P
#pragma unroll
    for (int mloc = 0; mloc < 2; ++mloc) {
      const f32x4 sv = mloc ? s1 : s0;
      int dpr = 2 * kc + mloc - qr;
      bool rok = (unsigned)dpr <= 6u;
      short4v pk;
#pragma unroll
      for (int r = 0; r < 4; ++r) {
        int dpc = fo * 4 + r - qc;
        float e = (rok && (unsigned)dpc <= 6u) ? __expf(sv[r]) : 0.f;
        sum += e;
        pk[r] = f2bf(e);
      }
      *(short4v*)(P + q_idx * 40 + mloc * 16 + fo * 4) = pk;
    }
    // --- PV (wave-private P rows; same-wave RAW handled by lgkmcnt)
    short8 pa = *(const short8*)(P + q_idx * 40 + fo * 8);
#pragma unroll
    for (int n = 0; n < 4; ++n)
      oacc[n] = __builtin_amdgcn_mfma_f32_16x16x32_bf16(pa, vf[n], oacc[n], 0, 0, 0);
  }

  // --- finish: full softmax denominators, redistribute to D-row lanes, store
  sum += __shfl_xor(sum, 16);
  sum += __shfl_xor(sum, 32);
  float inv[4];
#pragma unroll
  for (int r = 0; r < 4; ++r) inv[r] = 1.0f / __shfl(sum, fo * 4 + r);
  const int owr = i0 + 2 * w + (fo >> 1);
  const int owc = j0 + (fo & 1) * 4;
#pragma unroll
  for (int n = 0; n < 4; ++n)
#pragma unroll
    for (int r = 0; r < 4; ++r)
      aout[(size_t)(b * HWsz + owr * Hh + owc + r) * Cc + h * 64 + 16 * n + fr] =
          f2bf(oacc[n][r] * inv[r]);
}

extern "C" void kernel_launch(void* const* d_in, const int* in_sizes, int n_in,
                              void* d_out, int out_size, void* d_ws, size_t ws_size,
                              hipStream_t stream) {
  const float* x      = (const float*)d_in[0];
  const float* w_qkv  = (const float*)d_in[1];
  const float* b_qkv  = (const float*)d_in[2];
  const float* w_proj = (const float*)d_in[3];
  const float* b_proj = (const float*)d_in[4];

  char* ws = (char*)d_ws;
  // qk 38,535,168 | vtp 24,379,392 | xT/attn_out 19,267,584 | wqb 884,736 | wpb 294,912 = 83.4 MB
  short* qk  = (short*)ws;
  short* vtp = (short*)(ws + 38535168);
  short* xT  = (short*)(ws + 38535168 + 24379392);
  short* wqb = (short*)(ws + 38535168 + 24379392 + 19267584);
  short* wpb = (short*)(ws + 38535168 + 24379392 + 19267584 + 884736);

  prep_weights<<<512, 256, 0, stream>>>(w_qkv, w_proj, wqb, wpb);
  transpose_x<<<dim3(98, 12, NB), 256, 0, stream>>>(x, xT);
  hipMemsetAsync(vtp, 0, 24379392, stream);     // zero-pad borders for V image
  gemm_bf16<0><<<dim3(9, 25, NB), 256, 0, stream>>>(wqb, xT, b_qkv, qk, vtp);
  attn_mfma<<<dim3(7, 7, NB * NHEADS), 256, 0, stream>>>(qk, vtp, xT);  // xT reused as attn_out
  gemm_bf16<1><<<dim3(3, 25, NB), 256, 0, stream>>>(wpb, xT, b_proj, d_out, nullptr);
}